// Round 1
// baseline (452.712 us; speedup 1.0000x reference)
//
#include <hip/hip_runtime.h>
#include <cstdint>
#include <cstddef>

typedef __attribute__((ext_vector_type(8))) short bf16x8;
typedef __attribute__((ext_vector_type(8))) unsigned short us8;
typedef __attribute__((ext_vector_type(4))) float f32x4;

#define TSEQ 2048

__device__ __forceinline__ unsigned short f2bf(float f) {
  union { float f; uint32_t u; } v; v.f = f;
  uint32_t u = v.u;
  uint32_t r = (u + 0x7FFFu + ((u >> 16) & 1u)) >> 16;
  return (unsigned short)r;
}
__device__ __forceinline__ unsigned short f2bf_trunc(float f) {
  union { float f; uint32_t u; } v; v.f = f;
  return (unsigned short)(v.u >> 16);
}
__device__ __forceinline__ float bf2f(unsigned short h) {
  union { uint32_t u; float f; } v; v.u = ((uint32_t)h) << 16;
  return v.f;
}

__device__ __forceinline__ void async16(const void* g, void* l) {
  __builtin_amdgcn_global_load_lds(
      (const __attribute__((address_space(1))) unsigned int*)g,
      (__attribute__((address_space(3))) unsigned int*)l,
      16, 0, 0);
}

// ---------------------------------------------------------------------------
// x (fp32) -> xb (bf16), 16 elems/thread
// ---------------------------------------------------------------------------
__global__ __launch_bounds__(256) void cvt_x(
    const float* __restrict__ in, unsigned short* __restrict__ out)
{
  const size_t i = ((size_t)blockIdx.x * 256 + threadIdx.x) * 16;
  f32x4 a0 = *(const f32x4*)(in + i);
  f32x4 a1 = *(const f32x4*)(in + i + 4);
  f32x4 a2 = *(const f32x4*)(in + i + 8);
  f32x4 a3 = *(const f32x4*)(in + i + 12);
  us8 lo, hi;
#pragma unroll
  for (int j = 0; j < 4; j++) {
    lo[j] = f2bf(a0[j]); lo[j + 4] = f2bf(a1[j]);
    hi[j] = f2bf(a2[j]); hi[j + 4] = f2bf(a3[j]);
  }
  *(us8*)(out + i) = lo;
  *(us8*)(out + i + 8) = hi;
}

// ---------------------------------------------------------------------------
// out(C x R bf16) = transpose of in(R x C fp32)
// ---------------------------------------------------------------------------
__global__ __launch_bounds__(256) void transpose_w(
    const float* __restrict__ in, unsigned short* __restrict__ out,
    int R, int C)
{
  __shared__ unsigned short tile[32][33];
  const int bx = blockIdx.x * 32;
  const int by = blockIdx.y * 32;
  const int tx = threadIdx.x & 31;
  const int ty = threadIdx.x >> 5;
#pragma unroll
  for (int r = ty; r < 32; r += 8)
    tile[r][tx] = f2bf(in[(size_t)(by + r) * C + bx + tx]);
  __syncthreads();
#pragma unroll
  for (int r = ty; r < 32; r += 8)
    out[(size_t)(bx + r) * R + by + tx] = tile[tx][r];
}

// ---------------------------------------------------------------------------
// Legacy 128x128 gemm (kept for the proj GEMM where 256^2 grid = 128 blocks
// would only fill half the CUs).
// ---------------------------------------------------------------------------
template <int CF32>
__global__ __launch_bounds__(256) void gemm_bt(
    const unsigned short* __restrict__ A,
    const unsigned short* __restrict__ Bt,
    void* __restrict__ Cv,
    int M, int N, int K, int ldc)
{
  __shared__ unsigned short As[2][128 * 32];
  __shared__ unsigned short Bs[2][128 * 32];
  const int tid  = threadIdx.x;
  const int lane = tid & 63;
  const int w    = tid >> 6;
  const int m0   = blockIdx.y * 128;
  const int n0   = blockIdx.x * 128;
  const int wm   = (w & 1) * 64;
  const int wn   = (w >> 1) * 64;

  const int srow = lane >> 2;
  const int scol = (lane & 3) * 8;
  const unsigned short* ga0 = A  + (size_t)(m0 + w * 16 + srow) * K + scol;
  const unsigned short* ga1 = ga0 + (size_t)64 * K;
  const unsigned short* gb0 = Bt + (size_t)(n0 + w * 16 + srow) * K + scol;
  const unsigned short* gb1 = gb0 + (size_t)64 * K;

  f32x4 acc[4][4];
#pragma unroll
  for (int i = 0; i < 4; i++)
#pragma unroll
    for (int j = 0; j < 4; j++) acc[i][j] = (f32x4){0.f, 0.f, 0.f, 0.f};

  const int frow = lane & 15;
  const int fcol = (lane >> 4) * 8;

  for (int kt = 0; kt < K; kt += 64) {
    __syncthreads();
    async16(ga0 + kt,      &As[0][w * 512]);
    async16(ga1 + kt,      &As[0][(4 + w) * 512]);
    async16(ga0 + kt + 32, &As[1][w * 512]);
    async16(ga1 + kt + 32, &As[1][(4 + w) * 512]);
    async16(gb0 + kt,      &Bs[0][w * 512]);
    async16(gb1 + kt,      &Bs[0][(4 + w) * 512]);
    async16(gb0 + kt + 32, &Bs[1][w * 512]);
    async16(gb1 + kt + 32, &Bs[1][(4 + w) * 512]);
    __syncthreads();

#pragma unroll
    for (int h = 0; h < 2; h++) {
      bf16x8 af[4], bfr[4];
#pragma unroll
      for (int i = 0; i < 4; i++)
        af[i] = *(const bf16x8*)&As[h][(wm + i * 16 + frow) * 32 + fcol];
#pragma unroll
      for (int i = 0; i < 4; i++)
        bfr[i] = *(const bf16x8*)&Bs[h][(wn + i * 16 + frow) * 32 + fcol];
#pragma unroll
      for (int mi = 0; mi < 4; mi++)
#pragma unroll
        for (int ni = 0; ni < 4; ni++)
          acc[mi][ni] = __builtin_amdgcn_mfma_f32_16x16x32_bf16(
              af[mi], bfr[ni], acc[mi][ni], 0, 0, 0);
    }
  }

  const int crow0 = m0 + wm + (lane >> 4) * 4;
  const int ccol0 = n0 + wn + (lane & 15);
  if (CF32) {
    float* Cf = (float*)Cv;
#pragma unroll
    for (int mi = 0; mi < 4; mi++)
#pragma unroll
      for (int i = 0; i < 4; i++) {
        const int row = crow0 + mi * 16 + i;
#pragma unroll
        for (int ni = 0; ni < 4; ni++)
          Cf[(size_t)row * ldc + ccol0 + ni * 16] = acc[mi][ni][i];
      }
  } else {
    unsigned short* Cb = (unsigned short*)Cv;
#pragma unroll
    for (int mi = 0; mi < 4; mi++)
#pragma unroll
      for (int i = 0; i < 4; i++) {
        const int row = crow0 + mi * 16 + i;
#pragma unroll
        for (int ni = 0; ni < 4; ni++)
          Cb[(size_t)row * ldc + ccol0 + ni * 16] = f2bf(acc[mi][ni][i]);
      }
  }
}

// ---------------------------------------------------------------------------
// 256x256 BK=64 phase-split GEMM (T2+T3+T4+T5 combo, m201-style).
//   8 waves (2M x 4N), per-wave 128x64 output, acc[8][4].
//   LDS 128 KiB: 2 bufs x (A 256x64 + B 256x64) bf16.
//   Staging: global_load_lds x16B, linear LDS dest, source pre-swizzled so
//   that reads with addr ^= (row&7)<<4 are bank-even (8 words/bank).
//   4 phases/K-tile, 16 MFMA each; prefetch kt+2 issued in phase 3 (after
//   all ds_reads of that buffer have retired - barrier-ordered);
//   single s_waitcnt vmcnt(8) per K-tile -> 8 loads always in flight.
// ---------------------------------------------------------------------------
__device__ __forceinline__ void stage8(
    const unsigned short* gA, const unsigned short* gB,
    unsigned short* asb, unsigned short* bsb, int K, int kt, int lw)
{
#pragma unroll
  for (int j = 0; j < 4; j++)
    async16(gA + (size_t)j * 64 * K + (size_t)kt * 64, asb + j * 4096 + lw);
#pragma unroll
  for (int j = 0; j < 4; j++)
    async16(gB + (size_t)j * 64 * K + (size_t)kt * 64, bsb + j * 4096 + lw);
}

__global__ __launch_bounds__(512, 2) void gemm256(
    const unsigned short* __restrict__ A,
    const unsigned short* __restrict__ Bt,
    unsigned short* __restrict__ C,
    int K, int ldc, int ntiles, int nwg)
{
  __shared__ unsigned short As[2][256 * 64];
  __shared__ unsigned short Bs[2][256 * 64];

  // XCD-aware bijective swizzle (nwg % 8 == 0 by construction)
  int wg = blockIdx.x;
  wg = (wg & 7) * (nwg >> 3) + (wg >> 3);
  const int m0 = (wg / ntiles) * 256;
  const int n0 = (wg % ntiles) * 256;

  const int tid  = threadIdx.x;
  const int lane = tid & 63;
  const int w    = tid >> 6;
  const int wr   = w & 1;   // 2 M-groups
  const int wc   = w >> 1;  // 4 N-groups

  // staging map: thread t -> row t>>3, 16B-slot (t ^ (t>>3)) & 7
  // (inverse of the read-side XOR swizzle; rows unpermuted)
  const int srow  = tid >> 3;
  const int sslot = (tid ^ srow) & 7;
  const unsigned short* gA = A  + (size_t)(m0 + srow) * K + sslot * 8;
  const unsigned short* gB = Bt + (size_t)(n0 + srow) * K + sslot * 8;
  const int lw = w * 512;  // element offset of this wave's 1 KiB within an 8 KiB chunk

  f32x4 acc[8][4];
#pragma unroll
  for (int i = 0; i < 8; i++)
#pragma unroll
    for (int j = 0; j < 4; j++) acc[i][j] = (f32x4){0.f, 0.f, 0.f, 0.f};

  const int frow = lane & 15;
  const int fq16 = (lane >> 4) * 16;       // byte offset of 16B k-slot
  const int axr  = (frow & 7) << 4;        // XOR key (row&7; mi*16/wr*128 ≡ 0 mod 8)
  const int arow = (wr * 128 + frow) * 128;  // byte base, mi=0 kh=0
  const int brow = (wc * 64 + frow) * 128;

#define RDA(buf, mi, kh) \
  (*(const bf16x8*)((const char*)&As[buf][0] + ((arow + (mi) * 2048 + (kh) * 64 + fq16) ^ axr)))
#define RDB(buf, ni, kh) \
  (*(const bf16x8*)((const char*)&Bs[buf][0] + ((brow + (ni) * 2048 + (kh) * 64 + fq16) ^ axr)))

  stage8(gA, gB, &As[0][0], &Bs[0][0], K, 0, lw);
  stage8(gA, gB, &As[1][0], &Bs[1][0], K, 1, lw);
  asm volatile("s_waitcnt vmcnt(8)" ::: "memory");
  __builtin_amdgcn_s_barrier();

  const int NT = K >> 6;
  bf16x8 a[4][2], b[4][2];
  for (int kt = 0; kt < NT; ++kt) {
    const int p = kt & 1;

    // ---- phase 0: ds A-quad0 (8) + B0,1 (4); MFMA acc[0..3][0..1]
#pragma unroll
    for (int mi = 0; mi < 4; mi++) { a[mi][0] = RDA(p, mi, 0); a[mi][1] = RDA(p, mi, 1); }
#pragma unroll
    for (int ni = 0; ni < 2; ni++) { b[ni][0] = RDB(p, ni, 0); b[ni][1] = RDB(p, ni, 1); }
    __builtin_amdgcn_s_barrier();
    asm volatile("s_waitcnt lgkmcnt(0)" ::: "memory");
    __builtin_amdgcn_s_setprio(1);
#pragma unroll
    for (int mi = 0; mi < 4; mi++)
#pragma unroll
      for (int ni = 0; ni < 2; ni++)
#pragma unroll
        for (int kh = 0; kh < 2; kh++)
          acc[mi][ni] = __builtin_amdgcn_mfma_f32_16x16x32_bf16(
              a[mi][kh], b[ni][kh], acc[mi][ni], 0, 0, 0);
    __builtin_amdgcn_s_setprio(0);
    __builtin_amdgcn_s_barrier();

    // ---- phase 1: ds B2,3 (4); MFMA acc[0..3][2..3]
#pragma unroll
    for (int ni = 2; ni < 4; ni++) { b[ni][0] = RDB(p, ni, 0); b[ni][1] = RDB(p, ni, 1); }
    __builtin_amdgcn_s_barrier();
    asm volatile("s_waitcnt lgkmcnt(0)" ::: "memory");
    __builtin_amdgcn_s_setprio(1);
#pragma unroll
    for (int mi = 0; mi < 4; mi++)
#pragma unroll
      for (int ni = 2; ni < 4; ni++)
#pragma unroll
        for (int kh = 0; kh < 2; kh++)
          acc[mi][ni] = __builtin_amdgcn_mfma_f32_16x16x32_bf16(
              a[mi][kh], b[ni][kh], acc[mi][ni], 0, 0, 0);
    __builtin_amdgcn_s_setprio(0);
    __builtin_amdgcn_s_barrier();

    // ---- phase 2: ds A-quad1 (8); MFMA acc[4..7][2..3]
#pragma unroll
    for (int mi = 0; mi < 4; mi++) { a[mi][0] = RDA(p, mi + 4, 0); a[mi][1] = RDA(p, mi + 4, 1); }
    __builtin_amdgcn_s_barrier();
    asm volatile("s_waitcnt lgkmcnt(0)" ::: "memory");
    __builtin_amdgcn_s_setprio(1);
#pragma unroll
    for (int mi = 0; mi < 4; mi++)
#pragma unroll
      for (int ni = 2; ni < 4; ni++)
#pragma unroll
        for (int kh = 0; kh < 2; kh++)
          acc[mi + 4][ni] = __builtin_amdgcn_mfma_f32_16x16x32_bf16(
              a[mi][kh], b[ni][kh], acc[mi + 4][ni], 0, 0, 0);
    __builtin_amdgcn_s_setprio(0);
    __builtin_amdgcn_s_barrier();

    // ---- phase 3: issue prefetch kt+2 -> buf p (all reads of buf p retired:
    // every wave passed its phase-2 lgkmcnt(0) before the barrier above);
    // MFMA acc[4..7][0..1]; counted vmcnt keeps 8 loads in flight.
    if (kt + 2 < NT)
      stage8(gA, gB, &As[p][0], &Bs[p][0], K, kt + 2, lw);
    __builtin_amdgcn_s_setprio(1);
#pragma unroll
    for (int mi = 0; mi < 4; mi++)
#pragma unroll
      for (int ni = 0; ni < 2; ni++)
#pragma unroll
        for (int kh = 0; kh < 2; kh++)
          acc[mi + 4][ni] = __builtin_amdgcn_mfma_f32_16x16x32_bf16(
              a[mi][kh], b[ni][kh], acc[mi + 4][ni], 0, 0, 0);
    __builtin_amdgcn_s_setprio(0);
    if (kt + 2 < NT) {
      asm volatile("s_waitcnt vmcnt(8)" ::: "memory");  // kt+1's 8 arrived; kt+2's 8 in flight
    } else {
      asm volatile("s_waitcnt vmcnt(0)" ::: "memory");  // epilogue drain
    }
    __builtin_amdgcn_s_barrier();
  }
#undef RDA
#undef RDB

  // C/D layout (m89-verified): col = lane&15, row = (lane>>4)*4 + reg
  const int crow0 = m0 + wr * 128 + (lane >> 4) * 4;
  const int ccol0 = n0 + wc * 64 + frow;
#pragma unroll
  for (int mi = 0; mi < 8; mi++)
#pragma unroll
    for (int i = 0; i < 4; i++) {
      const size_t row = (size_t)(crow0 + mi * 16 + i);
#pragma unroll
      for (int ni = 0; ni < 4; ni++)
        C[row * ldc + ccol0 + ni * 16] = f2bf(acc[mi][ni][i]);
    }
}

// ---------------------------------------------------------------------------
// RoPE in-place on qkv cols [0,4096); 1/sqrt(128) folded into q half.
// theta via exp2f (single v_exp_f32) instead of powf's libm path.
// ---------------------------------------------------------------------------
__global__ __launch_bounds__(256) void rope_qk(unsigned short* __restrict__ qkv)
{
  const int p   = blockIdx.x * 256 + threadIdx.x;
  const int row = p >> 11;
  const int col = (p & 2047) * 2;
  const int t   = row & (TSEQ - 1);
  const int hd  = col & 127;
  // 10000^(-hd/128) = 2^(-hd * log2(10000)/128), log2(10000)/128 = 0.103810253
  const float theta = exp2f((float)hd * -0.1038102531f);
  const float ang   = (float)t * theta;
  float s, c;
  sincosf(ang, &s, &c);
  const float sc = (col < 2048) ? 0.08838834764831845f : 1.0f;
  uint32_t* ptr = (uint32_t*)(qkv + (size_t)row * 6144 + col);
  const uint32_t u = *ptr;
  const float x0 = bf2f((unsigned short)(u & 0xffffu));
  const float x1 = bf2f((unsigned short)(u >> 16));
  const float o0 = (x0 * c - x1 * s) * sc;
  const float o1 = (x1 * c + x0 * s) * sc;
  *ptr = (uint32_t)f2bf(o0) | ((uint32_t)f2bf(o1) << 16);
}

// ---------------------------------------------------------------------------
// Repack V: qkv cols [4096,6144) -> Vtg[b][h][d=128][t=2048]
// ---------------------------------------------------------------------------
__global__ __launch_bounds__(256) void repack_v(
    const unsigned short* __restrict__ qkv, unsigned short* __restrict__ Vtg)
{
  __shared__ unsigned short tile[32][33];
  const int tt = blockIdx.x * 32;
  const int dd = blockIdx.y * 32;
  const int bh = blockIdx.z;
  const int b  = bh >> 4, h = bh & 15;
  const int tx = threadIdx.x & 31;
  const int ty = threadIdx.x >> 5;
#pragma unroll
  for (int r = ty; r < 32; r += 8)
    tile[r][tx] = qkv[(size_t)(b * TSEQ + tt + r) * 6144 + 4096 + h * 128 + dd + tx];
  __syncthreads();
#pragma unroll
  for (int r = ty; r < 32; r += 8)
    Vtg[(size_t)bh * 262144 + (size_t)(dd + r) * TSEQ + tt + tx] = tile[tx][r];
}

// ---------------------------------------------------------------------------
// Flash attention. block = (b,h,128 q-rows), 4 waves x 32 q-rows, K-chunk 64.
// ---------------------------------------------------------------------------
__global__ __launch_bounds__(256) void attn(
    const unsigned short* __restrict__ qkv,  // (4096,6144) rope'd, q pre-scaled
    const unsigned short* __restrict__ Vtg,  // (32,128,2048)
    unsigned short* __restrict__ y)          // (4096,2048)
{
  __shared__ unsigned short Ks[64 * 136];
  __shared__ unsigned short Vs[144 * 72];
  __shared__ unsigned short Ps[4][32 * 72];

  const int tid  = threadIdx.x;
  const int lane = tid & 63;
  const int w    = tid >> 6;
  const int q0   = blockIdx.x * 128;
  const int h    = blockIdx.y;
  const int b    = blockIdx.z;
  const int bh   = b * 16 + h;
  const int quad = lane >> 4;
  const int l15  = lane & 15;
  const int kq   = quad * 8;

  for (int idx = tid; idx < 16 * 72; idx += 256)
    Vs[128 * 72 + idx] = (idx < 72) ? (unsigned short)0x3F80 : (unsigned short)0;

  bf16x8 qa[2][4];
#pragma unroll
  for (int mt = 0; mt < 2; mt++) {
    const unsigned short* gQ =
        qkv + (size_t)(b * TSEQ + q0 + w * 32 + mt * 16 + l15) * 6144 + h * 128 + kq;
#pragma unroll
    for (int dc = 0; dc < 4; dc++) qa[mt][dc] = *(const bf16x8*)(gQ + dc * 32);
  }

  f32x4 ot[2][9];
#pragma unroll
  for (int mt = 0; mt < 2; mt++)
#pragma unroll
    for (int nt = 0; nt < 9; nt++) ot[mt][nt] = (f32x4){0.f, 0.f, 0.f, 0.f};

  const int krow = tid >> 2;
  const int kd   = (tid & 3) * 32;
  const unsigned short* gK = qkv + (size_t)(b * TSEQ) * 6144 + 2048 + h * 128 + kd;
  const int vd = tid >> 1;
  const int vc = (tid & 1) * 32;
  const unsigned short* gVt = Vtg + (size_t)bh * 262144 + (size_t)vd * TSEQ + vc;

  for (int kb = 0; kb < TSEQ; kb += 64) {
    __syncthreads();
    {
      const unsigned short* pk = gK + (size_t)(kb + krow) * 6144;
#pragma unroll
      for (int j = 0; j < 4; j++)
        *(us8*)&Ks[krow * 136 + kd + j * 8] = *(const us8*)(pk + j * 8);
      const unsigned short* pv = gVt + kb;
#pragma unroll
      for (int j = 0; j < 4; j++)
        *(us8*)&Vs[vd * 72 + vc + j * 8] = *(const us8*)(pv + j * 8);
    }
    __syncthreads();

    f32x4 s[2][4];
#pragma unroll
    for (int mt = 0; mt < 2; mt++)
#pragma unroll
      for (int ct = 0; ct < 4; ct++) s[mt][ct] = (f32x4){0.f, 0.f, 0.f, 0.f};
#pragma unroll
    for (int dc = 0; dc < 4; dc++) {
#pragma unroll
      for (int ct = 0; ct < 4; ct++) {
        bf16x8 kf = *(const bf16x8*)&Ks[(ct * 16 + l15) * 136 + dc * 32 + kq];
        s[0][ct] = __builtin_amdgcn_mfma_f32_16x16x32_bf16(qa[0][dc], kf, s[0][ct], 0, 0, 0);
        s[1][ct] = __builtin_amdgcn_mfma_f32_16x16x32_bf16(qa[1][dc], kf, s[1][ct], 0, 0, 0);
      }
    }

    unsigned short* pw = &Ps[w][0];
#pragma unroll
    for (int mt = 0; mt < 2; mt++)
#pragma unroll
      for (int ct = 0; ct < 4; ct++)
#pragma unroll
        for (int i = 0; i < 4; i++)
          pw[(mt * 16 + quad * 4 + i) * 72 + ct * 16 + l15] =
              f2bf_trunc(__expf(fminf(s[mt][ct][i], 30.f)));

    __asm__ volatile("s_waitcnt lgkmcnt(0)" ::: "memory");

#pragma unroll
    for (int kc = 0; kc < 2; kc++) {
      bf16x8 pa0 = *(const bf16x8*)&pw[(l15) * 72 + kc * 32 + kq];
      bf16x8 pa1 = *(const bf16x8*)&pw[(16 + l15) * 72 + kc * 32 + kq];
#pragma unroll
      for (int nt = 0; nt < 9; nt++) {
        bf16x8 vb = *(const bf16x8*)&Vs[(nt * 16 + l15) * 72 + kc * 32 + kq];
        ot[0][nt] = __builtin_amdgcn_mfma_f32_16x16x32_bf16(pa0, vb, ot[0][nt], 0, 0, 0);
        ot[1][nt] = __builtin_amdgcn_mfma_f32_16x16x32_bf16(pa1, vb, ot[1][nt], 0, 0, 0);
      }
    }
  }

#pragma unroll
  for (int mt = 0; mt < 2; mt++) {
    unsigned short* gy =
        y + (size_t)(b * TSEQ + q0 + w * 32 + mt * 16 + quad * 4) * 2048 + h * 128 + l15;
#pragma unroll
    for (int i = 0; i < 4; i++) {
      const float inv = 1.0f / __shfl(ot[mt][8][i], lane & 48);
#pragma unroll
      for (int nt = 0; nt < 8; nt++)
        gy[(size_t)i * 2048 + nt * 16] = f2bf(ot[mt][nt][i] * inv);
    }
  }
}

// ---------------------------------------------------------------------------
extern "C" void kernel_launch(void* const* d_in, const int* in_sizes, int n_in,
                              void* d_out, int out_size, void* d_ws, size_t ws_size,
                              hipStream_t stream)
{
  const float* x      = (const float*)d_in[0];
  const float* w_attn = (const float*)d_in[1];
  const float* w_proj = (const float*)d_in[2];

  if (ws_size < 67108864u) return;

  char* ws = (char*)d_ws;
  unsigned short* qkv = (unsigned short*)(ws);              // 48 MiB
  unsigned short* xb  = (unsigned short*)(ws + 50331648);   // 16 MiB (then y)
  unsigned short* y   = xb;
  unsigned short* wT2 = (unsigned short*)(ws);              // 8 MiB, after attn
  unsigned short* wTa = (unsigned short*)d_out;             // 24 MiB scratch
  unsigned short* Vtg = (unsigned short*)d_out;             // 16 MiB scratch

  transpose_w<<<dim3(192, 64), 256, 0, stream>>>(w_attn, wTa, 2048, 6144);
  cvt_x<<<dim3(2048), 256, 0, stream>>>(x, xb);
  // QKV: M=4096 N=6144 K=2048, 16 x 24 = 384 tiles of 256^2
  gemm256<<<dim3(384), 512, 0, stream>>>(xb, wTa, qkv, 2048, 6144, 24, 384);
  rope_qk<<<dim3(32768), 256, 0, stream>>>(qkv);
  repack_v<<<dim3(64, 4, 32), 256, 0, stream>>>(qkv, Vtg);
  attn<<<dim3(16, 16, 2), 256, 0, stream>>>(qkv, Vtg, y);
  transpose_w<<<dim3(64, 64), 256, 0, stream>>>(w_proj, wT2, 2048, 2048);
  gemm_bt<1><<<dim3(16, 32), 256, 0, stream>>>(y, wT2, d_out, 4096, 2048, 2048, 2048);
}

// Round 2
// 445.716 us; speedup vs baseline: 1.0157x; 1.0157x over previous
//
#include <hip/hip_runtime.h>
#include <cstdint>
#include <cstddef>

typedef __attribute__((ext_vector_type(8))) short bf16x8;
typedef __attribute__((ext_vector_type(8))) unsigned short us8;
typedef __attribute__((ext_vector_type(4))) float f32x4;

#define TSEQ 2048

__device__ __forceinline__ unsigned short f2bf(float f) {
  union { float f; uint32_t u; } v; v.f = f;
  uint32_t u = v.u;
  uint32_t r = (u + 0x7FFFu + ((u >> 16) & 1u)) >> 16;
  return (unsigned short)r;
}
__device__ __forceinline__ unsigned short f2bf_trunc(float f) {
  union { float f; uint32_t u; } v; v.f = f;
  return (unsigned short)(v.u >> 16);
}
__device__ __forceinline__ float bf2f(unsigned short h) {
  union { uint32_t u; float f; } v; v.u = ((uint32_t)h) << 16;
  return v.f;
}

__device__ __forceinline__ void async16(const void* g, void* l) {
  __builtin_amdgcn_global_load_lds(
      (const __attribute__((address_space(1))) unsigned int*)g,
      (__attribute__((address_space(3))) unsigned int*)l,
      16, 0, 0);
}

// ---------------------------------------------------------------------------
// x (fp32) -> xb (bf16), 16 elems/thread
// ---------------------------------------------------------------------------
__global__ __launch_bounds__(256) void cvt_x(
    const float* __restrict__ in, unsigned short* __restrict__ out)
{
  const size_t i = ((size_t)blockIdx.x * 256 + threadIdx.x) * 16;
  f32x4 a0 = *(const f32x4*)(in + i);
  f32x4 a1 = *(const f32x4*)(in + i + 4);
  f32x4 a2 = *(const f32x4*)(in + i + 8);
  f32x4 a3 = *(const f32x4*)(in + i + 12);
  us8 lo, hi;
#pragma unroll
  for (int j = 0; j < 4; j++) {
    lo[j] = f2bf(a0[j]); lo[j + 4] = f2bf(a1[j]);
    hi[j] = f2bf(a2[j]); hi[j + 4] = f2bf(a3[j]);
  }
  *(us8*)(out + i) = lo;
  *(us8*)(out + i + 8) = hi;
}

// ---------------------------------------------------------------------------
// out(C x R bf16) = transpose of in(R x C fp32)
// ---------------------------------------------------------------------------
__global__ __launch_bounds__(256) void transpose_w(
    const float* __restrict__ in, unsigned short* __restrict__ out,
    int R, int C)
{
  __shared__ unsigned short tile[32][33];
  const int bx = blockIdx.x * 32;
  const int by = blockIdx.y * 32;
  const int tx = threadIdx.x & 31;
  const int ty = threadIdx.x >> 5;
#pragma unroll
  for (int r = ty; r < 32; r += 8)
    tile[r][tx] = f2bf(in[(size_t)(by + r) * C + bx + tx]);
  __syncthreads();
#pragma unroll
  for (int r = ty; r < 32; r += 8)
    out[(size_t)(bx + r) * R + by + tx] = tile[tx][r];
}

// ---------------------------------------------------------------------------
// Legacy 128x128 gemm (proj GEMM: 512 blocks @ 5 blocks/CU).
// ---------------------------------------------------------------------------
template <int CF32>
__global__ __launch_bounds__(256) void gemm_bt(
    const unsigned short* __restrict__ A,
    const unsigned short* __restrict__ Bt,
    void* __restrict__ Cv,
    int M, int N, int K, int ldc)
{
  __shared__ unsigned short As[2][128 * 32];
  __shared__ unsigned short Bs[2][128 * 32];
  const int tid  = threadIdx.x;
  const int lane = tid & 63;
  const int w    = tid >> 6;
  const int m0   = blockIdx.y * 128;
  const int n0   = blockIdx.x * 128;
  const int wm   = (w & 1) * 64;
  const int wn   = (w >> 1) * 64;

  const int srow = lane >> 2;
  const int scol = (lane & 3) * 8;
  const unsigned short* ga0 = A  + (size_t)(m0 + w * 16 + srow) * K + scol;
  const unsigned short* ga1 = ga0 + (size_t)64 * K;
  const unsigned short* gb0 = Bt + (size_t)(n0 + w * 16 + srow) * K + scol;
  const unsigned short* gb1 = gb0 + (size_t)64 * K;

  f32x4 acc[4][4];
#pragma unroll
  for (int i = 0; i < 4; i++)
#pragma unroll
    for (int j = 0; j < 4; j++) acc[i][j] = (f32x4){0.f, 0.f, 0.f, 0.f};

  const int frow = lane & 15;
  const int fcol = (lane >> 4) * 8;

  for (int kt = 0; kt < K; kt += 64) {
    __syncthreads();
    async16(ga0 + kt,      &As[0][w * 512]);
    async16(ga1 + kt,      &As[0][(4 + w) * 512]);
    async16(ga0 + kt + 32, &As[1][w * 512]);
    async16(ga1 + kt + 32, &As[1][(4 + w) * 512]);
    async16(gb0 + kt,      &Bs[0][w * 512]);
    async16(gb1 + kt,      &Bs[0][(4 + w) * 512]);
    async16(gb0 + kt + 32, &Bs[1][w * 512]);
    async16(gb1 + kt + 32, &Bs[1][(4 + w) * 512]);
    __syncthreads();

#pragma unroll
    for (int h = 0; h < 2; h++) {
      bf16x8 af[4], bfr[4];
#pragma unroll
      for (int i = 0; i < 4; i++)
        af[i] = *(const bf16x8*)&As[h][(wm + i * 16 + frow) * 32 + fcol];
#pragma unroll
      for (int i = 0; i < 4; i++)
        bfr[i] = *(const bf16x8*)&Bs[h][(wn + i * 16 + frow) * 32 + fcol];
#pragma unroll
      for (int mi = 0; mi < 4; mi++)
#pragma unroll
        for (int ni = 0; ni < 4; ni++)
          acc[mi][ni] = __builtin_amdgcn_mfma_f32_16x16x32_bf16(
              af[mi], bfr[ni], acc[mi][ni], 0, 0, 0);
    }
  }

  const int crow0 = m0 + wm + (lane >> 4) * 4;
  const int ccol0 = n0 + wn + (lane & 15);
  if (CF32) {
    float* Cf = (float*)Cv;
#pragma unroll
    for (int mi = 0; mi < 4; mi++)
#pragma unroll
      for (int i = 0; i < 4; i++) {
        const int row = crow0 + mi * 16 + i;
#pragma unroll
        for (int ni = 0; ni < 4; ni++)
          Cf[(size_t)row * ldc + ccol0 + ni * 16] = acc[mi][ni][i];
      }
  } else {
    unsigned short* Cb = (unsigned short*)Cv;
#pragma unroll
    for (int mi = 0; mi < 4; mi++)
#pragma unroll
      for (int i = 0; i < 4; i++) {
        const int row = crow0 + mi * 16 + i;
#pragma unroll
        for (int ni = 0; ni < 4; ni++)
          Cb[(size_t)row * ldc + ccol0 + ni * 16] = f2bf(acc[mi][ni][i]);
      }
  }
}

// ---------------------------------------------------------------------------
// 256x256 BK=64 phase-split GEMM. Round-2 change: SPREAD the kt+2 prefetch
// across phases (m196: the fine ds_read || G::load || MFMA interleave is the
// lever; bunched loads cost -7..-27%).
//   Hazard proof per chunk (stage only after phase-end barrier that retires
//   all reads of that LDS region):
//     A rows [0,64)+[128,192)  last read P0  -> stage at P1
//     B rows (all, frags 0..1) read P0, frags 2..3 read P1 -> B safe after P1
//     A rows [64,128)+[192,256) last read P2 -> stage at P3
//   vmcnt(8) once per K-tile at P3-end: 8 kt+2 loads outstanding, kt+1 landed.
// ---------------------------------------------------------------------------
__device__ __forceinline__ void stage8(
    const unsigned short* gA, const unsigned short* gB,
    unsigned short* asb, unsigned short* bsb, int K, int kt, int lw)
{
#pragma unroll
  for (int j = 0; j < 4; j++)
    async16(gA + (size_t)j * 64 * K + (size_t)kt * 64, asb + j * 4096 + lw);
#pragma unroll
  for (int j = 0; j < 4; j++)
    async16(gB + (size_t)j * 64 * K + (size_t)kt * 64, bsb + j * 4096 + lw);
}

__global__ __launch_bounds__(512, 2) void gemm256(
    const unsigned short* __restrict__ A,
    const unsigned short* __restrict__ Bt,
    unsigned short* __restrict__ C,
    int K, int ldc, int ntiles, int nwg)
{
  __shared__ unsigned short As[2][256 * 64];
  __shared__ unsigned short Bs[2][256 * 64];

  // XCD-aware bijective swizzle (nwg % 8 == 0 by construction)
  int wg = blockIdx.x;
  wg = (wg & 7) * (nwg >> 3) + (wg >> 3);
  const int m0 = (wg / ntiles) * 256;
  const int n0 = (wg % ntiles) * 256;

  const int tid  = threadIdx.x;
  const int lane = tid & 63;
  const int w    = tid >> 6;
  const int wr   = w & 1;   // 2 M-groups
  const int wc   = w >> 1;  // 4 N-groups

  // staging map: thread t -> row t>>3, 16B-slot (t ^ (t>>3)) & 7
  const int srow  = tid >> 3;
  const int sslot = (tid ^ srow) & 7;
  const unsigned short* gA = A  + (size_t)(m0 + srow) * K + sslot * 8;
  const unsigned short* gB = Bt + (size_t)(n0 + srow) * K + sslot * 8;
  const int lw = w * 512;  // element offset of this wave's 1 KiB within an 8 KiB chunk

  f32x4 acc[8][4];
#pragma unroll
  for (int i = 0; i < 8; i++)
#pragma unroll
    for (int j = 0; j < 4; j++) acc[i][j] = (f32x4){0.f, 0.f, 0.f, 0.f};

  const int frow = lane & 15;
  const int fq16 = (lane >> 4) * 16;       // byte offset of 16B k-slot
  const int axr  = (frow & 7) << 4;        // XOR key
  const int arow = (wr * 128 + frow) * 128;  // byte base, mi=0 kh=0
  const int brow = (wc * 64 + frow) * 128;

#define RDA(buf, mi, kh) \
  (*(const bf16x8*)((const char*)&As[buf][0] + ((arow + (mi) * 2048 + (kh) * 64 + fq16) ^ axr)))
#define RDB(buf, ni, kh) \
  (*(const bf16x8*)((const char*)&Bs[buf][0] + ((brow + (ni) * 2048 + (kh) * 64 + fq16) ^ axr)))
#define STG_A(c, kt2) async16(gA + (size_t)(c) * 64 * K + (size_t)(kt2) * 64, &As[p][(c) * 4096 + lw])
#define STG_B(c, kt2) async16(gB + (size_t)(c) * 64 * K + (size_t)(kt2) * 64, &Bs[p][(c) * 4096 + lw])

  stage8(gA, gB, &As[0][0], &Bs[0][0], K, 0, lw);
  stage8(gA, gB, &As[1][0], &Bs[1][0], K, 1, lw);
  asm volatile("s_waitcnt vmcnt(8)" ::: "memory");
  __builtin_amdgcn_s_barrier();

  const int NT = K >> 6;
  bf16x8 a[4][2], b[4][2];
  for (int kt = 0; kt < NT; ++kt) {
    const int p = kt & 1;
    const bool pf = (kt + 2 < NT);

    // ---- phase 0: ds A-quad0 (8) + B0,1 (4); MFMA acc[0..3][0..1]
#pragma unroll
    for (int mi = 0; mi < 4; mi++) { a[mi][0] = RDA(p, mi, 0); a[mi][1] = RDA(p, mi, 1); }
#pragma unroll
    for (int ni = 0; ni < 2; ni++) { b[ni][0] = RDB(p, ni, 0); b[ni][1] = RDB(p, ni, 1); }
    __builtin_amdgcn_s_barrier();
    asm volatile("s_waitcnt lgkmcnt(0)" ::: "memory");
    __builtin_amdgcn_s_setprio(1);
#pragma unroll
    for (int mi = 0; mi < 4; mi++)
#pragma unroll
      for (int ni = 0; ni < 2; ni++)
#pragma unroll
        for (int kh = 0; kh < 2; kh++)
          acc[mi][ni] = __builtin_amdgcn_mfma_f32_16x16x32_bf16(
              a[mi][kh], b[ni][kh], acc[mi][ni], 0, 0, 0);
    __builtin_amdgcn_s_setprio(0);
    __builtin_amdgcn_s_barrier();

    // ---- phase 1: ds B2,3 (4); stage A-chunks 0,2 (kt+2); MFMA acc[0..3][2..3]
#pragma unroll
    for (int ni = 2; ni < 4; ni++) { b[ni][0] = RDB(p, ni, 0); b[ni][1] = RDB(p, ni, 1); }
    if (pf) { STG_A(0, kt + 2); STG_A(2, kt + 2); }
    __builtin_amdgcn_s_barrier();
    asm volatile("s_waitcnt lgkmcnt(0)" ::: "memory");
    __builtin_amdgcn_s_setprio(1);
#pragma unroll
    for (int mi = 0; mi < 4; mi++)
#pragma unroll
      for (int ni = 2; ni < 4; ni++)
#pragma unroll
        for (int kh = 0; kh < 2; kh++)
          acc[mi][ni] = __builtin_amdgcn_mfma_f32_16x16x32_bf16(
              a[mi][kh], b[ni][kh], acc[mi][ni], 0, 0, 0);
    __builtin_amdgcn_s_setprio(0);
    __builtin_amdgcn_s_barrier();

    // ---- phase 2: ds A-quad1 (8); stage B-chunks 0,1; MFMA acc[4..7][2..3]
#pragma unroll
    for (int mi = 0; mi < 4; mi++) { a[mi][0] = RDA(p, mi + 4, 0); a[mi][1] = RDA(p, mi + 4, 1); }
    if (pf) { STG_B(0, kt + 2); STG_B(1, kt + 2); }
    __builtin_amdgcn_s_barrier();
    asm volatile("s_waitcnt lgkmcnt(0)" ::: "memory");
    __builtin_amdgcn_s_setprio(1);
#pragma unroll
    for (int mi = 0; mi < 4; mi++)
#pragma unroll
      for (int ni = 2; ni < 4; ni++)
#pragma unroll
        for (int kh = 0; kh < 2; kh++)
          acc[mi + 4][ni] = __builtin_amdgcn_mfma_f32_16x16x32_bf16(
              a[mi][kh], b[ni][kh], acc[mi + 4][ni], 0, 0, 0);
    __builtin_amdgcn_s_setprio(0);
    __builtin_amdgcn_s_barrier();

    // ---- phase 3: stage B2,B3,A1,A3; MFMA acc[4..7][0..1]; counted vmcnt
    if (pf) { STG_B(2, kt + 2); STG_B(3, kt + 2); STG_A(1, kt + 2); STG_A(3, kt + 2); }
    __builtin_amdgcn_s_setprio(1);
#pragma unroll
    for (int mi = 0; mi < 4; mi++)
#pragma unroll
      for (int ni = 0; ni < 2; ni++)
#pragma unroll
        for (int kh = 0; kh < 2; kh++)
          acc[mi + 4][ni] = __builtin_amdgcn_mfma_f32_16x16x32_bf16(
              a[mi][kh], b[ni][kh], acc[mi + 4][ni], 0, 0, 0);
    __builtin_amdgcn_s_setprio(0);
    if (pf) {
      asm volatile("s_waitcnt vmcnt(8)" ::: "memory");  // kt+1 landed; kt+2 in flight
    } else {
      asm volatile("s_waitcnt vmcnt(0)" ::: "memory");  // epilogue drain
    }
    __builtin_amdgcn_s_barrier();
  }
#undef RDA
#undef RDB
#undef STG_A
#undef STG_B

  // C/D layout (m89-verified): col = lane&15, row = (lane>>4)*4 + reg
  const int crow0 = m0 + wr * 128 + (lane >> 4) * 4;
  const int ccol0 = n0 + wc * 64 + frow;
#pragma unroll
  for (int mi = 0; mi < 8; mi++)
#pragma unroll
    for (int i = 0; i < 4; i++) {
      const size_t row = (size_t)(crow0 + mi * 16 + i);
#pragma unroll
      for (int ni = 0; ni < 4; ni++)
        C[row * ldc + ccol0 + ni * 16] = f2bf(acc[mi][ni][i]);
    }
}

// ---------------------------------------------------------------------------
// RoPE in-place on qkv cols [0,4096); 1/sqrt(128) folded into q half.
// ---------------------------------------------------------------------------
__global__ __launch_bounds__(256) void rope_qk(unsigned short* __restrict__ qkv)
{
  const int p   = blockIdx.x * 256 + threadIdx.x;
  const int row = p >> 11;
  const int col = (p & 2047) * 2;
  const int t   = row & (TSEQ - 1);
  const int hd  = col & 127;
  const float theta = exp2f((float)hd * -0.1038102531f);
  const float ang   = (float)t * theta;
  float s, c;
  sincosf(ang, &s, &c);
  const float sc = (col < 2048) ? 0.08838834764831845f : 1.0f;
  uint32_t* ptr = (uint32_t*)(qkv + (size_t)row * 6144 + col);
  const uint32_t u = *ptr;
  const float x0 = bf2f((unsigned short)(u & 0xffffu));
  const float x1 = bf2f((unsigned short)(u >> 16));
  const float o0 = (x0 * c - x1 * s) * sc;
  const float o1 = (x1 * c + x0 * s) * sc;
  *ptr = (uint32_t)f2bf(o0) | ((uint32_t)f2bf(o1) << 16);
}

// ---------------------------------------------------------------------------
// Repack V: qkv cols [4096,6144) -> Vtg[b][h][d=128][t=2048]
// ---------------------------------------------------------------------------
__global__ __launch_bounds__(256) void repack_v(
    const unsigned short* __restrict__ qkv, unsigned short* __restrict__ Vtg)
{
  __shared__ unsigned short tile[32][33];
  const int tt = blockIdx.x * 32;
  const int dd = blockIdx.y * 32;
  const int bh = blockIdx.z;
  const int b  = bh >> 4, h = bh & 15;
  const int tx = threadIdx.x & 31;
  const int ty = threadIdx.x >> 5;
#pragma unroll
  for (int r = ty; r < 32; r += 8)
    tile[r][tx] = qkv[(size_t)(b * TSEQ + tt + r) * 6144 + 4096 + h * 128 + dd + tx];
  __syncthreads();
#pragma unroll
  for (int r = ty; r < 32; r += 8)
    Vtg[(size_t)bh * 262144 + (size_t)(dd + r) * TSEQ + tt + tx] = tile[tx][r];
}

// ---------------------------------------------------------------------------
// Flash attention. block = (b,h,128 q-rows), 4 waves x 32 q-rows, K-chunk 64.
// ---------------------------------------------------------------------------
__global__ __launch_bounds__(256) void attn(
    const unsigned short* __restrict__ qkv,  // (4096,6144) rope'd, q pre-scaled
    const unsigned short* __restrict__ Vtg,  // (32,128,2048)
    unsigned short* __restrict__ y)          // (4096,2048)
{
  __shared__ unsigned short Ks[64 * 136];
  __shared__ unsigned short Vs[144 * 72];
  __shared__ unsigned short Ps[4][32 * 72];

  const int tid  = threadIdx.x;
  const int lane = tid & 63;
  const int w    = tid >> 6;
  const int q0   = blockIdx.x * 128;
  const int h    = blockIdx.y;
  const int b    = blockIdx.z;
  const int bh   = b * 16 + h;
  const int quad = lane >> 4;
  const int l15  = lane & 15;
  const int kq   = quad * 8;

  for (int idx = tid; idx < 16 * 72; idx += 256)
    Vs[128 * 72 + idx] = (idx < 72) ? (unsigned short)0x3F80 : (unsigned short)0;

  bf16x8 qa[2][4];
#pragma unroll
  for (int mt = 0; mt < 2; mt++) {
    const unsigned short* gQ =
        qkv + (size_t)(b * TSEQ + q0 + w * 32 + mt * 16 + l15) * 6144 + h * 128 + kq;
#pragma unroll
    for (int dc = 0; dc < 4; dc++) qa[mt][dc] = *(const bf16x8*)(gQ + dc * 32);
  }

  f32x4 ot[2][9];
#pragma unroll
  for (int mt = 0; mt < 2; mt++)
#pragma unroll
    for (int nt = 0; nt < 9; nt++) ot[mt][nt] = (f32x4){0.f, 0.f, 0.f, 0.f};

  const int krow = tid >> 2;
  const int kd   = (tid & 3) * 32;
  const unsigned short* gK = qkv + (size_t)(b * TSEQ) * 6144 + 2048 + h * 128 + kd;
  const int vd = tid >> 1;
  const int vc = (tid & 1) * 32;
  const unsigned short* gVt = Vtg + (size_t)bh * 262144 + (size_t)vd * TSEQ + vc;

  for (int kb = 0; kb < TSEQ; kb += 64) {
    __syncthreads();
    {
      const unsigned short* pk = gK + (size_t)(kb + krow) * 6144;
#pragma unroll
      for (int j = 0; j < 4; j++)
        *(us8*)&Ks[krow * 136 + kd + j * 8] = *(const us8*)(pk + j * 8);
      const unsigned short* pv = gVt + kb;
#pragma unroll
      for (int j = 0; j < 4; j++)
        *(us8*)&Vs[vd * 72 + vc + j * 8] = *(const us8*)(pv + j * 8);
    }
    __syncthreads();

    f32x4 s[2][4];
#pragma unroll
    for (int mt = 0; mt < 2; mt++)
#pragma unroll
      for (int ct = 0; ct < 4; ct++) s[mt][ct] = (f32x4){0.f, 0.f, 0.f, 0.f};
#pragma unroll
    for (int dc = 0; dc < 4; dc++) {
#pragma unroll
      for (int ct = 0; ct < 4; ct++) {
        bf16x8 kf = *(const bf16x8*)&Ks[(ct * 16 + l15) * 136 + dc * 32 + kq];
        s[0][ct] = __builtin_amdgcn_mfma_f32_16x16x32_bf16(qa[0][dc], kf, s[0][ct], 0, 0, 0);
        s[1][ct] = __builtin_amdgcn_mfma_f32_16x16x32_bf16(qa[1][dc], kf, s[1][ct], 0, 0, 0);
      }
    }

    unsigned short* pw = &Ps[w][0];
#pragma unroll
    for (int mt = 0; mt < 2; mt++)
#pragma unroll
      for (int ct = 0; ct < 4; ct++)
#pragma unroll
        for (int i = 0; i < 4; i++)
          pw[(mt * 16 + quad * 4 + i) * 72 + ct * 16 + l15] =
              f2bf_trunc(__expf(fminf(s[mt][ct][i], 30.f)));

    __asm__ volatile("s_waitcnt lgkmcnt(0)" ::: "memory");

#pragma unroll
    for (int kc = 0; kc < 2; kc++) {
      bf16x8 pa0 = *(const bf16x8*)&pw[(l15) * 72 + kc * 32 + kq];
      bf16x8 pa1 = *(const bf16x8*)&pw[(16 + l15) * 72 + kc * 32 + kq];
#pragma unroll
      for (int nt = 0; nt < 9; nt++) {
        bf16x8 vb = *(const bf16x8*)&Vs[(nt * 16 + l15) * 72 + kc * 32 + kq];
        ot[0][nt] = __builtin_amdgcn_mfma_f32_16x16x32_bf16(pa0, vb, ot[0][nt], 0, 0, 0);
        ot[1][nt] = __builtin_amdgcn_mfma_f32_16x16x32_bf16(pa1, vb, ot[1][nt], 0, 0, 0);
      }
    }
  }

#pragma unroll
  for (int mt = 0; mt < 2; mt++) {
    unsigned short* gy =
        y + (size_t)(b * TSEQ + q0 + w * 32 + mt * 16 + quad * 4) * 2048 + h * 128 + l15;
#pragma unroll
    for (int i = 0; i < 4; i++) {
      const float inv = 1.0f / __shfl(ot[mt][8][i], lane & 48);
#pragma unroll
      for (int nt = 0; nt < 8; nt++)
        gy[(size_t)i * 2048 + nt * 16] = f2bf(ot[mt][nt][i] * inv);
    }
  }
}

// ---------------------------------------------------------------------------
extern "C" void kernel_launch(void* const* d_in, const int* in_sizes, int n_in,
                              void* d_out, int out_size, void* d_ws, size_t ws_size,
                              hipStream_t stream)
{
  const float* x      = (const float*)d_in[0];
  const float* w_attn = (const float*)d_in[1];
  const float* w_proj = (const float*)d_in[2];

  if (ws_size < 67108864u) return;

  char* ws = (char*)d_ws;
  unsigned short* qkv = (unsigned short*)(ws);              // 48 MiB
  unsigned short* xb  = (unsigned short*)(ws + 50331648);   // 16 MiB (then y)
  unsigned short* y   = xb;
  unsigned short* wT2 = (unsigned short*)(ws);              // 8 MiB, after attn
  unsigned short* wTa = (unsigned short*)d_out;             // 24 MiB scratch
  unsigned short* Vtg = (unsigned short*)d_out;             // 16 MiB scratch

  transpose_w<<<dim3(192, 64), 256, 0, stream>>>(w_attn, wTa, 2048, 6144);
  cvt_x<<<dim3(2048), 256, 0, stream>>>(x, xb);
  // QKV: M=4096 N=6144 K=2048, 16 x 24 = 384 tiles of 256^2
  gemm256<<<dim3(384), 512, 0, stream>>>(xb, wTa, qkv, 2048, 6144, 24, 384);
  rope_qk<<<dim3(32768), 256, 0, stream>>>(qkv);
  repack_v<<<dim3(64, 4, 32), 256, 0, stream>>>(qkv, Vtg);
  attn<<<dim3(16, 16, 2), 256, 0, stream>>>(qkv, Vtg, y);
  transpose_w<<<dim3(64, 64), 256, 0, stream>>>(w_proj, wT2, 2048, 2048);
  gemm_bt<1><<<dim3(16, 32), 256, 0, stream>>>(y, wT2, d_out, 4096, 2048, 2048, 2048);
}